// Round 1
// baseline (5419.012 us; speedup 1.0000x reference)
//
#include <hip/hip_runtime.h>
#include <math.h>

#define DI static __device__ __forceinline__

// ---------- bf16 helpers ----------
DI unsigned short f2bf(float f){
  union { float f; unsigned u; } v; v.f = f;
  unsigned r = (v.u + 0x7fffu + ((v.u >> 16) & 1u)) >> 16;
  return (unsigned short)r;
}
DI float bflo(unsigned v){ return __uint_as_float(v << 16); }
DI float bfhi(unsigned v){ return __uint_as_float(v & 0xffff0000u); }
DI unsigned pk2(float a, float b){ return (unsigned)f2bf(a) | ((unsigned)f2bf(b) << 16); }
DI void unpack8(uint4 u, float* a){
  a[0]=bflo(u.x); a[1]=bfhi(u.x); a[2]=bflo(u.y); a[3]=bfhi(u.y);
  a[4]=bflo(u.z); a[5]=bfhi(u.z); a[6]=bflo(u.w); a[7]=bfhi(u.w);
}
DI void load16(const float* p, float* v){
  const float4* q = (const float4*)p;
  float4 a=q[0], b=q[1], c=q[2], d=q[3];
  v[0]=a.x; v[1]=a.y; v[2]=a.z; v[3]=a.w;
  v[4]=b.x; v[5]=b.y; v[6]=b.z; v[7]=b.w;
  v[8]=c.x; v[9]=c.y; v[10]=c.z; v[11]=c.w;
  v[12]=d.x; v[13]=d.y; v[14]=d.z; v[15]=d.w;
}
DI void load16bf(const unsigned short* p, float* v){
  const uint4* q = (const uint4*)p;
  unpack8(q[0], v); unpack8(q[1], v+8);
}
DI void store16bf(unsigned short* p, const float* r){
  uint4 u0, u1;
  u0.x=pk2(r[0],r[1]);  u0.y=pk2(r[2],r[3]);  u0.z=pk2(r[4],r[5]);  u0.w=pk2(r[6],r[7]);
  u1.x=pk2(r[8],r[9]);  u1.y=pk2(r[10],r[11]); u1.z=pk2(r[12],r[13]); u1.w=pk2(r[14],r[15]);
  *(uint4*)p = u0; *(uint4*)(p+8) = u1;
}

// ---------- prep: weight transpose (src[o][k] -> dst[k][o]) ----------
__global__ void k_transpose_f32(const float* __restrict__ src, float* __restrict__ dst,
                                int O, int K, float scale){
  int idx = blockIdx.x * 256 + threadIdx.x;
  if (idx >= O*K) return;
  int o = idx / K, k = idx - o*K;
  dst[k*O + o] = src[idx] * scale;
}
__global__ void k_scale_vec(const float* __restrict__ src, float* __restrict__ dst, int n, float s){
  int i = blockIdx.x*256 + threadIdx.x;
  if (i < n) dst[i] = src[i]*s;
}

// ---------- kernel 1: pointwise convs + LN1, write xn/yn (bf16) + z0 (bf16) ----------
// block = 256 thr, one block per 64 consecutive tokens. thread tile: 4 tok x 16 out.
__global__ __launch_bounds__(256) void k_conv_ln(
    const float* __restrict__ LH, const float* __restrict__ HL,
    const float* __restrict__ HH, const float* __restrict__ Sp,
    const float* __restrict__ wtx, const float* __restrict__ bx,
    const float* __restrict__ wtz, const float* __restrict__ bz,
    const float* __restrict__ wty, const float* __restrict__ by,
    const float* __restrict__ g1x, const float* __restrict__ b1x,
    const float* __restrict__ g1y, const float* __restrict__ b1y,
    unsigned short* __restrict__ xn, unsigned short* __restrict__ yn,
    unsigned short* __restrict__ z0)
{
  __shared__ float part[16][64][2];
  __shared__ float stats[64][2];
  const int tid = threadIdx.x;
  const int tt = tid & 15, oo = tid >> 4;
  const int mB = blockIdx.x << 6;
  const int b  = mB >> 14;
  const size_t pb = (size_t)b * (64*16384) + (mB & 16383) + tt*4;

  float acc[4][16];
  auto zero_acc = [&](){
    #pragma unroll
    for (int i=0;i<4;++i)
      #pragma unroll
      for (int j=0;j<16;++j) acc[i][j] = 0.f;
  };
  auto accum64 = [&](const float* plane, const float* wt, int c0){
    #pragma unroll 2
    for (int c=0;c<64;++c){
      float4 a4 = *(const float4*)(plane + (size_t)c*16384);
      float wv[16]; load16(wt + (c0+c)*256 + oo*16, wv);
      float av[4] = {a4.x, a4.y, a4.z, a4.w};
      #pragma unroll
      for (int i=0;i<4;++i)
        #pragma unroll
        for (int j=0;j<16;++j) acc[i][j] += av[i]*wv[j];
    }
  };
  auto ln_store = [&](const float* bias, const float* g, const float* bb,
                      unsigned short* dst){
    float bv[16]; load16(bias + oo*16, bv);
    #pragma unroll
    for (int i=0;i<4;++i){
      float s=0.f, q=0.f;
      #pragma unroll
      for (int j=0;j<16;++j){ float v = acc[i][j]+bv[j]; acc[i][j]=v; s+=v; q+=v*v; }
      part[oo][tt*4+i][0]=s; part[oo][tt*4+i][1]=q;
    }
    __syncthreads();
    if (tid < 64){
      float s=0.f, q=0.f;
      #pragma unroll
      for (int gi=0;gi<16;++gi){ s += part[gi][tid][0]; q += part[gi][tid][1]; }
      float mean = s*(1.f/256.f);
      float var  = q*(1.f/256.f) - mean*mean;
      stats[tid][0]=mean;
      stats[tid][1]=rsqrtf(var + 1e-5f);
    }
    __syncthreads();
    float gv[16], av2[16];
    load16(g + oo*16, gv); load16(bb + oo*16, av2);
    #pragma unroll
    for (int i=0;i<4;++i){
      int tok = tt*4+i;
      float mean = stats[tok][0], rstd = stats[tok][1];
      float r[16];
      #pragma unroll
      for (int j=0;j<16;++j) r[j] = (acc[i][j]-mean)*rstd*gv[j] + av2[j];
      store16bf(dst + (size_t)(mB+tok)*256 + oo*16, r);
    }
    __syncthreads();
  };

  // x = conv([LH,HL]) -> LN1x -> xn
  zero_acc();
  accum64(LH + pb, wtx, 0);
  accum64(HL + pb, wtx, 64);
  ln_store(bx, g1x, b1x, xn);
  // y = conv(Spat) -> LN1y -> yn
  zero_acc();
  accum64(Sp + pb, wty, 0);
  ln_store(by, g1y, b1y, yn);
  // z0 = conv(HH) (no LN)
  zero_acc();
  accum64(HH + pb, wtz, 0);
  {
    float bv[16]; load16(bz + oo*16, bv);
    #pragma unroll
    for (int i=0;i<4;++i){
      int tok = tt*4+i;
      float r[16];
      #pragma unroll
      for (int j=0;j<16;++j) r[j] = acc[i][j] + bv[j];
      store16bf(z0 + (size_t)(mB+tok)*256 + oo*16, r);
    }
  }
}

// ---------- kernel 2: fused window attention ----------
// one block per 8x8 window: QKV in-block GEMMs, online-softmax+RPB, PV, proj, +shortcut -> zt
#define BS 264   // padded LDS row stride (ushorts); 264*2=528B keeps 16B alignment, breaks pow2 banks
__global__ __launch_bounds__(256) void k_attn(
    const unsigned short* __restrict__ xn, const unsigned short* __restrict__ yn,
    const unsigned short* __restrict__ z0,
    const float* __restrict__ wqt, const float* __restrict__ bq,
    const float* __restrict__ wkt, const float* __restrict__ bk,
    const float* __restrict__ wvt, const float* __restrict__ bv,
    const float* __restrict__ wpt, const float* __restrict__ bp,
    const float* __restrict__ rpb, float* __restrict__ zt)
{
  __shared__ __align__(16) unsigned short bufQ[64*BS];  // xw -> q
  __shared__ __align__(16) unsigned short bufV[64*BS];  // yw -> v
  __shared__ __align__(16) unsigned short bufK[64*BS];  // k -> attn out
  __shared__ float rpb_s[1800];
  const int tid = threadIdx.x;
  const int wid = blockIdx.x;
  const int b = wid >> 8, rem = wid & 255, whi = rem >> 4, wwi = rem & 15;
  const size_t tokbase = (size_t)b*16384 + (size_t)whi*1024 + (size_t)wwi*8;

  for (int i = tid; i < 1800; i += 256) rpb_s[i] = rpb[i];
  #pragma unroll
  for (int r = 0; r < 8; ++r){
    size_t g = (tokbase + (size_t)r*128) * 256 + tid*8;
    int tok = r*8 + (tid >> 5);
    int ch  = (tid & 31) * 8;
    *(uint4*)(bufQ + tok*BS + ch) = *(const uint4*)(xn + g);
    *(uint4*)(bufV + tok*BS + ch) = *(const uint4*)(yn + g);
  }
  __syncthreads();

  const int tt = tid & 15, oo = tid >> 4;
  float acc[4][16];
  auto gemmLDS = [&](const unsigned short* A, const float* wt, const float* bias){
    #pragma unroll
    for (int i=0;i<4;++i)
      #pragma unroll
      for (int j=0;j<16;++j) acc[i][j]=0.f;
    #pragma unroll 1
    for (int k8=0;k8<32;++k8){
      const int k = k8*8;
      float a0[8],a1[8],a2[8],a3[8];
      unpack8(*(const uint4*)(A + (tt*4+0)*BS + k), a0);
      unpack8(*(const uint4*)(A + (tt*4+1)*BS + k), a1);
      unpack8(*(const uint4*)(A + (tt*4+2)*BS + k), a2);
      unpack8(*(const uint4*)(A + (tt*4+3)*BS + k), a3);
      #pragma unroll
      for (int kk=0;kk<8;++kk){
        float wv[16]; load16(wt + (k+kk)*256 + oo*16, wv);
        #pragma unroll
        for (int j=0;j<16;++j){
          acc[0][j] += a0[kk]*wv[j];
          acc[1][j] += a1[kk]*wv[j];
          acc[2][j] += a2[kk]*wv[j];
          acc[3][j] += a3[kk]*wv[j];
        }
      }
    }
    float bvv[16]; load16(bias + oo*16, bvv);
    #pragma unroll
    for (int i=0;i<4;++i)
      #pragma unroll
      for (int j=0;j<16;++j) acc[i][j] += bvv[j];
  };
  auto storeA = [&](unsigned short* dst){
    #pragma unroll
    for (int i=0;i<4;++i)
      store16bf(dst + (tt*4+i)*BS + oo*16, acc[i]);
  };

  gemmLDS(bufQ, wqt, bq);     // q (scale folded into wqt/bq)
  __syncthreads();            // all reads of xw done
  storeA(bufQ);
  gemmLDS(bufV, wkt, bk);     // k
  storeA(bufK);
  gemmLDS(bufV, wvt, bv);     // v
  __syncthreads();            // all reads of yw done
  storeA(bufV);
  __syncthreads();            // q,k,v visible

  // ---- attention: 512 rows (h,qt), 2 per thread, online softmax + RPB ----
  float orow[2][32];
  #pragma unroll 1
  for (int rr=0; rr<2; ++rr){
    const int r = tid + rr*256;
    const int h = r >> 6, qt = r & 63;
    const int qr = qt >> 3, qc = qt & 7;
    float qv[32]; load16bf(bufQ + qt*BS + h*32, qv); load16bf(bufQ + qt*BS + h*32 + 16, qv+16);
    float m = -1e30f, l = 0.f, oa[32];
    #pragma unroll
    for (int d=0;d<32;++d) oa[d]=0.f;
    const float* rpr = rpb_s + h;
    #pragma unroll 1
    for (int kt=0;kt<64;++kt){
      float kv[32]; load16bf(bufK + kt*BS + h*32, kv); load16bf(bufK + kt*BS + h*32 + 16, kv+16);
      float s = 0.f;
      #pragma unroll
      for (int d=0;d<32;++d) s += qv[d]*kv[d];
      const int kr = kt >> 3, kc = kt & 7;
      s += rpr[((qr-kr+7)*15 + (qc-kc+7))*8];
      float mn = fmaxf(m, s);
      float cf = __expf(m - mn);
      float e  = __expf(s - mn);
      l = l*cf + e;
      float vvv[32]; load16bf(bufV + kt*BS + h*32, vvv); load16bf(bufV + kt*BS + h*32 + 16, vvv+16);
      #pragma unroll
      for (int d=0;d<32;++d) oa[d] = oa[d]*cf + e*vvv[d];
      m = mn;
    }
    float inv = 1.f/l;
    #pragma unroll
    for (int d=0;d<32;++d) orow[rr][d] = oa[d]*inv;
  }
  __syncthreads();            // all attn reads done
  #pragma unroll
  for (int rr=0;rr<2;++rr){
    const int r = tid + rr*256; const int h = r>>6, qt = r&63;
    store16bf(bufK + qt*BS + h*32, orow[rr]);
    store16bf(bufK + qt*BS + h*32 + 16, orow[rr]+16);
  }
  __syncthreads();

  // ---- proj + shortcut(z0) -> zt (fp32) ----
  gemmLDS(bufK, wpt, bp);
  #pragma unroll
  for (int i=0;i<4;++i){
    const int tl = tt*4+i;
    const size_t gt = tokbase + (size_t)(tl>>3)*128 + (size_t)(tl&7);
    float zv[16]; load16bf(z0 + gt*256 + oo*16, zv);
    float4 o0, o1, o2, o3;
    o0.x=acc[i][0]+zv[0];  o0.y=acc[i][1]+zv[1];  o0.z=acc[i][2]+zv[2];  o0.w=acc[i][3]+zv[3];
    o1.x=acc[i][4]+zv[4];  o1.y=acc[i][5]+zv[5];  o1.z=acc[i][6]+zv[6];  o1.w=acc[i][7]+zv[7];
    o2.x=acc[i][8]+zv[8];  o2.y=acc[i][9]+zv[9];  o2.z=acc[i][10]+zv[10]; o2.w=acc[i][11]+zv[11];
    o3.x=acc[i][12]+zv[12]; o3.y=acc[i][13]+zv[13]; o3.z=acc[i][14]+zv[14]; o3.w=acc[i][15]+zv[15];
    float4* dp = (float4*)(zt + gt*256 + oo*16);
    dp[0]=o0; dp[1]=o1; dp[2]=o2; dp[3]=o3;
  }
}

// ---------- kernel 3: LN2 + MLP + residual + NCHW transpose ----------
__global__ __launch_bounds__(256) void k_mlp(
    const float* __restrict__ zt,
    const float* __restrict__ g2, const float* __restrict__ b2,
    const float* __restrict__ fc1t, const float* __restrict__ fc1b,
    const float* __restrict__ fc2t, const float* __restrict__ fc2b,
    float* __restrict__ out)
{
  __shared__ __align__(16) unsigned short smu[2*64*264];  // ztn | hb ; reused as float ob[64][257]
  unsigned short* ztn = smu;
  unsigned short* hb  = smu + 64*264;
  float* ob = (float*)smu;

  const int tid = threadIdx.x;
  const int mB = blockIdx.x << 6;

  { // LN2: 4 threads per token
    const int tok = tid >> 2, qd = tid & 3;
    const float* zr = zt + (size_t)(mB+tok)*256 + qd*64;
    float v[64];
    #pragma unroll
    for (int j4=0;j4<16;++j4){
      float4 t = ((const float4*)zr)[j4];
      v[j4*4+0]=t.x; v[j4*4+1]=t.y; v[j4*4+2]=t.z; v[j4*4+3]=t.w;
    }
    float s=0.f, q=0.f;
    #pragma unroll
    for (int j=0;j<64;++j){ s += v[j]; q += v[j]*v[j]; }
    s += __shfl_xor(s,1); q += __shfl_xor(q,1);
    s += __shfl_xor(s,2); q += __shfl_xor(q,2);
    float mean = s*(1.f/256.f);
    float rstd = rsqrtf(q*(1.f/256.f) - mean*mean + 1e-5f);
    float gv[64], bv[64];
    #pragma unroll
    for (int j4=0;j4<16;++j4){
      float4 t = ((const float4*)(g2 + qd*64))[j4];
      gv[j4*4+0]=t.x; gv[j4*4+1]=t.y; gv[j4*4+2]=t.z; gv[j4*4+3]=t.w;
      float4 u = ((const float4*)(b2 + qd*64))[j4];
      bv[j4*4+0]=u.x; bv[j4*4+1]=u.y; bv[j4*4+2]=u.z; bv[j4*4+3]=u.w;
    }
    unsigned short* zd = ztn + tok*264 + qd*64;
    #pragma unroll
    for (int j8=0;j8<8;++j8){
      float r[8];
      #pragma unroll
      for (int e=0;e<8;++e) r[e] = (v[j8*8+e]-mean)*rstd*gv[j8*8+e] + bv[j8*8+e];
      uint4 u;
      u.x=pk2(r[0],r[1]); u.y=pk2(r[2],r[3]); u.z=pk2(r[4],r[5]); u.w=pk2(r[6],r[7]);
      *(uint4*)(zd + j8*8) = u;
    }
  }
  __syncthreads();

  const int tt = tid & 15, oo = tid >> 4;
  float oacc[4][16];
  #pragma unroll
  for (int i=0;i<4;++i)
    #pragma unroll
    for (int j=0;j<16;++j) oacc[i][j]=0.f;

  #pragma unroll 1
  for (int n=0;n<4;++n){
    float ha[4][16];
    #pragma unroll
    for (int i=0;i<4;++i)
      #pragma unroll
      for (int j=0;j<16;++j) ha[i][j]=0.f;
    #pragma unroll 1
    for (int k8=0;k8<32;++k8){
      const int k = k8*8;
      float a0[8],a1[8],a2[8],a3[8];
      unpack8(*(const uint4*)(ztn + (tt*4+0)*264 + k), a0);
      unpack8(*(const uint4*)(ztn + (tt*4+1)*264 + k), a1);
      unpack8(*(const uint4*)(ztn + (tt*4+2)*264 + k), a2);
      unpack8(*(const uint4*)(ztn + (tt*4+3)*264 + k), a3);
      #pragma unroll
      for (int kk=0;kk<8;++kk){
        float wv[16]; load16(fc1t + (size_t)(k+kk)*1024 + n*256 + oo*16, wv);
        #pragma unroll
        for (int j=0;j<16;++j){
          ha[0][j] += a0[kk]*wv[j];
          ha[1][j] += a1[kk]*wv[j];
          ha[2][j] += a2[kk]*wv[j];
          ha[3][j] += a3[kk]*wv[j];
        }
      }
    }
    float bv[16]; load16(fc1b + n*256 + oo*16, bv);
    __syncthreads();   // prior fc2 reads of hb complete
    #pragma unroll
    for (int i=0;i<4;++i){
      float r[16];
      #pragma unroll
      for (int j=0;j<16;++j){
        float x = ha[i][j] + bv[j];
        r[j] = 0.5f*x*(1.f + erff(x*0.70710678118654752f));  // exact GELU
      }
      store16bf(hb + (tt*4+i)*264 + oo*16, r);
    }
    __syncthreads();
    #pragma unroll 1
    for (int k8=0;k8<32;++k8){
      const int k = k8*8;
      float a0[8],a1[8],a2[8],a3[8];
      unpack8(*(const uint4*)(hb + (tt*4+0)*264 + k), a0);
      unpack8(*(const uint4*)(hb + (tt*4+1)*264 + k), a1);
      unpack8(*(const uint4*)(hb + (tt*4+2)*264 + k), a2);
      unpack8(*(const uint4*)(hb + (tt*4+3)*264 + k), a3);
      #pragma unroll
      for (int kk=0;kk<8;++kk){
        float wv[16]; load16(fc2t + (size_t)(n*256+k+kk)*256 + oo*16, wv);
        #pragma unroll
        for (int j=0;j<16;++j){
          oacc[0][j] += a0[kk]*wv[j];
          oacc[1][j] += a1[kk]*wv[j];
          oacc[2][j] += a2[kk]*wv[j];
          oacc[3][j] += a3[kk]*wv[j];
        }
      }
    }
  }
  __syncthreads();  // done with ztn/hb; reuse as ob

  { // residual + bias, stage to padded ob for transposed write
    float bv[16]; load16(fc2b + oo*16, bv);
    #pragma unroll
    for (int i=0;i<4;++i){
      const int tok = tt*4+i;
      float zv[16]; load16(zt + (size_t)(mB+tok)*256 + oo*16, zv);
      float* od = ob + tok*257 + oo*16;
      #pragma unroll
      for (int j=0;j<16;++j) od[j] = oacc[i][j] + bv[j] + zv[j];
    }
  }
  __syncthreads();
  { // NCHW write: per wave one contiguous 64-float row
    const int b = mB >> 14, hw0 = mB & 16383;
    float* obase = out + (size_t)b*(256*16384) + hw0;
    #pragma unroll 1
    for (int it=0; it<64; ++it){
      int l = it*256 + tid;
      int o = l >> 6, tk = l & 63;
      obase[(size_t)o*16384 + tk] = ob[tk*257 + o];
    }
  }
}

// ---------- host ----------
extern "C" void kernel_launch(void* const* d_in, const int* in_sizes, int n_in,
                              void* d_out, int out_size, void* d_ws, size_t ws_size,
                              hipStream_t stream)
{
  (void)in_sizes; (void)n_in; (void)out_size; (void)ws_size;
  const float* LH    = (const float*)d_in[0];
  const float* HL    = (const float*)d_in[1];
  const float* HH    = (const float*)d_in[2];
  const float* Spat  = (const float*)d_in[3];
  const float* w_hllh= (const float*)d_in[4];
  const float* b_hllh= (const float*)d_in[5];
  const float* w_hh  = (const float*)d_in[6];
  const float* b_hh  = (const float*)d_in[7];
  const float* w_spat= (const float*)d_in[8];
  const float* b_spat= (const float*)d_in[9];
  const float* ln1x_g= (const float*)d_in[10];
  const float* ln1x_b= (const float*)d_in[11];
  const float* ln1y_g= (const float*)d_in[12];
  const float* ln1y_b= (const float*)d_in[13];
  const float* qkv_w = (const float*)d_in[14];
  const float* qkv_b = (const float*)d_in[15];
  const float* qkv2_w= (const float*)d_in[16];
  const float* qkv2_b= (const float*)d_in[17];
  const float* qkv3_w= (const float*)d_in[18];
  const float* qkv3_b= (const float*)d_in[19];
  const float* proj_w= (const float*)d_in[20];
  const float* proj_b= (const float*)d_in[21];
  const float* rpb   = (const float*)d_in[22];
  const float* ln2_g = (const float*)d_in[23];
  const float* ln2_b = (const float*)d_in[24];
  const float* fc1_w = (const float*)d_in[25];
  const float* fc1_b = (const float*)d_in[26];
  const float* fc2_w = (const float*)d_in[27];
  const float* fc2_b = (const float*)d_in[28];
  float* out = (float*)d_out;

  char* ws = (char*)d_ws;
  size_t off = 0;
  auto alloc = [&](size_t bytes)->void*{
    void* p = ws + off; off += (bytes + 255) & ~(size_t)255; return p;
  };
  const size_t M = 131072;
  unsigned short* xn = (unsigned short*)alloc(M*256*2);
  unsigned short* yn = (unsigned short*)alloc(M*256*2);
  unsigned short* z0 = (unsigned short*)alloc(M*256*2);
  float* zt  = (float*)alloc(M*256*4);
  float* wtx = (float*)alloc(128*256*4);
  float* wtz = (float*)alloc(64*256*4);
  float* wty = (float*)alloc(64*256*4);
  float* wqt = (float*)alloc(256*256*4);
  float* wkt = (float*)alloc(256*256*4);
  float* wvt = (float*)alloc(256*256*4);
  float* wpt = (float*)alloc(256*256*4);
  float* fc1t= (float*)alloc(256*1024*4);
  float* fc2t= (float*)alloc(1024*256*4);
  float* bqs = (float*)alloc(256*4);

  const float sc = 0.17677669529663687f;  // 1/sqrt(hd=32), folded into q weights+bias
  k_transpose_f32<<<dim3(128),  dim3(256), 0, stream>>>(w_hllh, wtx, 256, 128, 1.f);
  k_transpose_f32<<<dim3(64),   dim3(256), 0, stream>>>(w_hh,   wtz, 256, 64, 1.f);
  k_transpose_f32<<<dim3(64),   dim3(256), 0, stream>>>(w_spat, wty, 256, 64, 1.f);
  k_transpose_f32<<<dim3(256),  dim3(256), 0, stream>>>(qkv_w,  wqt, 256, 256, sc);
  k_transpose_f32<<<dim3(256),  dim3(256), 0, stream>>>(qkv2_w, wkt, 256, 256, 1.f);
  k_transpose_f32<<<dim3(256),  dim3(256), 0, stream>>>(qkv3_w, wvt, 256, 256, 1.f);
  k_transpose_f32<<<dim3(256),  dim3(256), 0, stream>>>(proj_w, wpt, 256, 256, 1.f);
  k_transpose_f32<<<dim3(1024), dim3(256), 0, stream>>>(fc1_w,  fc1t, 1024, 256, 1.f);
  k_transpose_f32<<<dim3(1024), dim3(256), 0, stream>>>(fc2_w,  fc2t, 256, 1024, 1.f);
  k_scale_vec   <<<dim3(1),    dim3(256), 0, stream>>>(qkv_b, bqs, 256, sc);

  k_conv_ln<<<dim3(2048), dim3(256), 0, stream>>>(LH, HL, HH, Spat,
      wtx, b_hllh, wtz, b_hh, wty, b_spat,
      ln1x_g, ln1x_b, ln1y_g, ln1y_b, xn, yn, z0);
  k_attn<<<dim3(2048), dim3(256), 0, stream>>>(xn, yn, z0,
      wqt, bqs, wkt, qkv2_b, wvt, qkv3_b, wpt, proj_b, rpb, zt);
  k_mlp<<<dim3(2048), dim3(256), 0, stream>>>(zt, ln2_g, ln2_b,
      fc1t, fc1_b, fc2t, fc2_b, out);
}

// Round 2
// 2957.702 us; speedup vs baseline: 1.8322x; 1.8322x over previous
//
#include <hip/hip_runtime.h>
#include <math.h>

#define DI static __device__ __forceinline__

typedef __attribute__((ext_vector_type(8))) short bhalf8;
typedef __attribute__((ext_vector_type(4))) float floatx4;

// ---------- bf16 helpers ----------
DI unsigned short f2bf(float f){
  union { float f; unsigned u; } v; v.f = f;
  unsigned r = (v.u + 0x7fffu + ((v.u >> 16) & 1u)) >> 16;
  return (unsigned short)r;
}
DI float bflo(unsigned v){ return __uint_as_float(v << 16); }
DI float bfhi(unsigned v){ return __uint_as_float(v & 0xffff0000u); }
DI unsigned pk2(float a, float b){ return (unsigned)f2bf(a) | ((unsigned)f2bf(b) << 16); }
DI void unpack8(uint4 u, float* a){
  a[0]=bflo(u.x); a[1]=bfhi(u.x); a[2]=bflo(u.y); a[3]=bfhi(u.y);
  a[4]=bflo(u.z); a[5]=bfhi(u.z); a[6]=bflo(u.w); a[7]=bfhi(u.w);
}
DI void load16(const float* p, float* v){
  const float4* q = (const float4*)p;
  float4 a=q[0], b=q[1], c=q[2], d=q[3];
  v[0]=a.x; v[1]=a.y; v[2]=a.z; v[3]=a.w;
  v[4]=b.x; v[5]=b.y; v[6]=b.z; v[7]=b.w;
  v[8]=c.x; v[9]=c.y; v[10]=c.z; v[11]=c.w;
  v[12]=d.x; v[13]=d.y; v[14]=d.z; v[15]=d.w;
}
DI void load16bf(const unsigned short* p, float* v){
  const uint4* q = (const uint4*)p;
  unpack8(q[0], v); unpack8(q[1], v+8);
}
DI void store16bf(unsigned short* p, const float* r){
  uint4 u0, u1;
  u0.x=pk2(r[0],r[1]);  u0.y=pk2(r[2],r[3]);  u0.z=pk2(r[4],r[5]);  u0.w=pk2(r[6],r[7]);
  u1.x=pk2(r[8],r[9]);  u1.y=pk2(r[10],r[11]); u1.z=pk2(r[12],r[13]); u1.w=pk2(r[14],r[15]);
  *(uint4*)p = u0; *(uint4*)(p+8) = u1;
}
// tanh-form GELU: max |err| vs exact ~3e-4, negligible after fc2 vs bf16 threshold
DI float gelu(float x){
  float u = x*(0.7978845608f + 0.0356774081f*x*x);
  float e = __expf(2.f*u);
  return x - x/(e + 1.f);
}

// ---------- prep: weight transpose (src[o][k] -> dst[k][o]) ----------
__global__ void k_transpose_f32(const float* __restrict__ src, float* __restrict__ dst,
                                int O, int K, float scale){
  int idx = blockIdx.x * 256 + threadIdx.x;
  if (idx >= O*K) return;
  int o = idx / K, k = idx - o*K;
  dst[k*O + o] = src[idx] * scale;
}
__global__ void k_scale_vec(const float* __restrict__ src, float* __restrict__ dst, int n, float s){
  int i = blockIdx.x*256 + threadIdx.x;
  if (i < n) dst[i] = src[i]*s;
}
// prep: pack weight (O x K f32, row-major, out-major) into bf16 MFMA B-fragment order:
// dst[((nt*KS + ks)*64 + lane)*8 + j] = bf16(src[(nt*16 + (lane&15))*K + ks*32 + (lane>>4)*8 + j])
__global__ void k_fragw(const float* __restrict__ src, unsigned short* __restrict__ dst,
                        int n, int K){
  int t = blockIdx.x*256 + threadIdx.x;
  if (t >= n) return;
  int j = t & 7, lane = (t >> 3) & 63, rest = t >> 9;
  int KS = K >> 5;
  int ks = rest % KS, nt = rest / KS;
  int row = nt*16 + (lane & 15);
  int col = ks*32 + ((lane >> 4) << 3) + j;
  dst[t] = f2bf(src[(size_t)row*K + col]);
}

// ---------- kernel 1: pointwise convs + LN1, write xn/yn (bf16) + z0 (bf16) ----------
__global__ __launch_bounds__(256) void k_conv_ln(
    const float* __restrict__ LH, const float* __restrict__ HL,
    const float* __restrict__ HH, const float* __restrict__ Sp,
    const float* __restrict__ wtx, const float* __restrict__ bx,
    const float* __restrict__ wtz, const float* __restrict__ bz,
    const float* __restrict__ wty, const float* __restrict__ by,
    const float* __restrict__ g1x, const float* __restrict__ b1x,
    const float* __restrict__ g1y, const float* __restrict__ b1y,
    unsigned short* __restrict__ xn, unsigned short* __restrict__ yn,
    unsigned short* __restrict__ z0)
{
  __shared__ float part[16][64][2];
  __shared__ float stats[64][2];
  const int tid = threadIdx.x;
  const int tt = tid & 15, oo = tid >> 4;
  const int mB = blockIdx.x << 6;
  const int b  = mB >> 14;
  const size_t pb = (size_t)b * (64*16384) + (mB & 16383) + tt*4;

  float acc[4][16];
  auto zero_acc = [&](){
    #pragma unroll
    for (int i=0;i<4;++i)
      #pragma unroll
      for (int j=0;j<16;++j) acc[i][j] = 0.f;
  };
  auto accum64 = [&](const float* plane, const float* wt, int c0){
    #pragma unroll 2
    for (int c=0;c<64;++c){
      float4 a4 = *(const float4*)(plane + (size_t)c*16384);
      float wv[16]; load16(wt + (c0+c)*256 + oo*16, wv);
      float av[4] = {a4.x, a4.y, a4.z, a4.w};
      #pragma unroll
      for (int i=0;i<4;++i)
        #pragma unroll
        for (int j=0;j<16;++j) acc[i][j] += av[i]*wv[j];
    }
  };
  auto ln_store = [&](const float* bias, const float* g, const float* bb,
                      unsigned short* dst){
    float bv[16]; load16(bias + oo*16, bv);
    #pragma unroll
    for (int i=0;i<4;++i){
      float s=0.f, q=0.f;
      #pragma unroll
      for (int j=0;j<16;++j){ float v = acc[i][j]+bv[j]; acc[i][j]=v; s+=v; q+=v*v; }
      part[oo][tt*4+i][0]=s; part[oo][tt*4+i][1]=q;
    }
    __syncthreads();
    if (tid < 64){
      float s=0.f, q=0.f;
      #pragma unroll
      for (int gi=0;gi<16;++gi){ s += part[gi][tid][0]; q += part[gi][tid][1]; }
      float mean = s*(1.f/256.f);
      float var  = q*(1.f/256.f) - mean*mean;
      stats[tid][0]=mean;
      stats[tid][1]=rsqrtf(var + 1e-5f);
    }
    __syncthreads();
    float gv[16], av2[16];
    load16(g + oo*16, gv); load16(bb + oo*16, av2);
    #pragma unroll
    for (int i=0;i<4;++i){
      int tok = tt*4+i;
      float mean = stats[tok][0], rstd = stats[tok][1];
      float r[16];
      #pragma unroll
      for (int j=0;j<16;++j) r[j] = (acc[i][j]-mean)*rstd*gv[j] + av2[j];
      store16bf(dst + (size_t)(mB+tok)*256 + oo*16, r);
    }
    __syncthreads();
  };

  zero_acc();
  accum64(LH + pb, wtx, 0);
  accum64(HL + pb, wtx, 64);
  ln_store(bx, g1x, b1x, xn);
  zero_acc();
  accum64(Sp + pb, wty, 0);
  ln_store(by, g1y, b1y, yn);
  zero_acc();
  accum64(HH + pb, wtz, 0);
  {
    float bv[16]; load16(bz + oo*16, bv);
    #pragma unroll
    for (int i=0;i<4;++i){
      int tok = tt*4+i;
      float r[16];
      #pragma unroll
      for (int j=0;j<16;++j) r[j] = acc[i][j] + bv[j];
      store16bf(z0 + (size_t)(mB+tok)*256 + oo*16, r);
    }
  }
}

// ---------- kernel 2: fused window attention (unchanged this round) ----------
#define BS 264
__global__ __launch_bounds__(256) void k_attn(
    const unsigned short* __restrict__ xn, const unsigned short* __restrict__ yn,
    const unsigned short* __restrict__ z0,
    const float* __restrict__ wqt, const float* __restrict__ bq,
    const float* __restrict__ wkt, const float* __restrict__ bk,
    const float* __restrict__ wvt, const float* __restrict__ bv,
    const float* __restrict__ wpt, const float* __restrict__ bp,
    const float* __restrict__ rpb, float* __restrict__ zt)
{
  __shared__ __align__(16) unsigned short bufQ[64*BS];
  __shared__ __align__(16) unsigned short bufV[64*BS];
  __shared__ __align__(16) unsigned short bufK[64*BS];
  __shared__ float rpb_s[1800];
  const int tid = threadIdx.x;
  const int wid = blockIdx.x;
  const int b = wid >> 8, rem = wid & 255, whi = rem >> 4, wwi = rem & 15;
  const size_t tokbase = (size_t)b*16384 + (size_t)whi*1024 + (size_t)wwi*8;

  for (int i = tid; i < 1800; i += 256) rpb_s[i] = rpb[i];
  #pragma unroll
  for (int r = 0; r < 8; ++r){
    size_t g = (tokbase + (size_t)r*128) * 256 + tid*8;
    int tok = r*8 + (tid >> 5);
    int ch  = (tid & 31) * 8;
    *(uint4*)(bufQ + tok*BS + ch) = *(const uint4*)(xn + g);
    *(uint4*)(bufV + tok*BS + ch) = *(const uint4*)(yn + g);
  }
  __syncthreads();

  const int tt = tid & 15, oo = tid >> 4;
  float acc[4][16];
  auto gemmLDS = [&](const unsigned short* A, const float* wt, const float* bias){
    #pragma unroll
    for (int i=0;i<4;++i)
      #pragma unroll
      for (int j=0;j<16;++j) acc[i][j]=0.f;
    #pragma unroll 1
    for (int k8=0;k8<32;++k8){
      const int k = k8*8;
      float a0[8],a1[8],a2[8],a3[8];
      unpack8(*(const uint4*)(A + (tt*4+0)*BS + k), a0);
      unpack8(*(const uint4*)(A + (tt*4+1)*BS + k), a1);
      unpack8(*(const uint4*)(A + (tt*4+2)*BS + k), a2);
      unpack8(*(const uint4*)(A + (tt*4+3)*BS + k), a3);
      #pragma unroll
      for (int kk=0;kk<8;++kk){
        float wv[16]; load16(wt + (k+kk)*256 + oo*16, wv);
        #pragma unroll
        for (int j=0;j<16;++j){
          acc[0][j] += a0[kk]*wv[j];
          acc[1][j] += a1[kk]*wv[j];
          acc[2][j] += a2[kk]*wv[j];
          acc[3][j] += a3[kk]*wv[j];
        }
      }
    }
    float bvv[16]; load16(bias + oo*16, bvv);
    #pragma unroll
    for (int i=0;i<4;++i)
      #pragma unroll
      for (int j=0;j<16;++j) acc[i][j] += bvv[j];
  };
  auto storeA = [&](unsigned short* dst){
    #pragma unroll
    for (int i=0;i<4;++i)
      store16bf(dst + (tt*4+i)*BS + oo*16, acc[i]);
  };

  gemmLDS(bufQ, wqt, bq);
  __syncthreads();
  storeA(bufQ);
  gemmLDS(bufV, wkt, bk);
  storeA(bufK);
  gemmLDS(bufV, wvt, bv);
  __syncthreads();
  storeA(bufV);
  __syncthreads();

  float orow[2][32];
  #pragma unroll 1
  for (int rr=0; rr<2; ++rr){
    const int r = tid + rr*256;
    const int h = r >> 6, qt = r & 63;
    const int qr = qt >> 3, qc = qt & 7;
    float qv[32]; load16bf(bufQ + qt*BS + h*32, qv); load16bf(bufQ + qt*BS + h*32 + 16, qv+16);
    float m = -1e30f, l = 0.f, oa[32];
    #pragma unroll
    for (int d=0;d<32;++d) oa[d]=0.f;
    const float* rpr = rpb_s + h;
    #pragma unroll 1
    for (int kt=0;kt<64;++kt){
      float kv[32]; load16bf(bufK + kt*BS + h*32, kv); load16bf(bufK + kt*BS + h*32 + 16, kv+16);
      float s = 0.f;
      #pragma unroll
      for (int d=0;d<32;++d) s += qv[d]*kv[d];
      const int kr = kt >> 3, kc = kt & 7;
      s += rpr[((qr-kr+7)*15 + (qc-kc+7))*8];
      float mn = fmaxf(m, s);
      float cf = __expf(m - mn);
      float e  = __expf(s - mn);
      l = l*cf + e;
      float vvv[32]; load16bf(bufV + kt*BS + h*32, vvv); load16bf(bufV + kt*BS + h*32 + 16, vvv+16);
      #pragma unroll
      for (int d=0;d<32;++d) oa[d] = oa[d]*cf + e*vvv[d];
      m = mn;
    }
    float inv = 1.f/l;
    #pragma unroll
    for (int d=0;d<32;++d) orow[rr][d] = oa[d]*inv;
  }
  __syncthreads();
  #pragma unroll
  for (int rr=0;rr<2;++rr){
    const int r = tid + rr*256; const int h = r>>6, qt = r&63;
    store16bf(bufK + qt*BS + h*32, orow[rr]);
    store16bf(bufK + qt*BS + h*32 + 16, orow[rr]+16);
  }
  __syncthreads();

  gemmLDS(bufK, wpt, bp);
  #pragma unroll
  for (int i=0;i<4;++i){
    const int tl = tt*4+i;
    const size_t gt = tokbase + (size_t)(tl>>3)*128 + (size_t)(tl&7);
    float zv[16]; load16bf(z0 + gt*256 + oo*16, zv);
    float4 o0, o1, o2, o3;
    o0.x=acc[i][0]+zv[0];  o0.y=acc[i][1]+zv[1];  o0.z=acc[i][2]+zv[2];  o0.w=acc[i][3]+zv[3];
    o1.x=acc[i][4]+zv[4];  o1.y=acc[i][5]+zv[5];  o1.z=acc[i][6]+zv[6];  o1.w=acc[i][7]+zv[7];
    o2.x=acc[i][8]+zv[8];  o2.y=acc[i][9]+zv[9];  o2.z=acc[i][10]+zv[10]; o2.w=acc[i][11]+zv[11];
    o3.x=acc[i][12]+zv[12]; o3.y=acc[i][13]+zv[13]; o3.z=acc[i][14]+zv[14]; o3.w=acc[i][15]+zv[15];
    float4* dp = (float4*)(zt + gt*256 + oo*16);
    dp[0]=o0; dp[1]=o1; dp[2]=o2; dp[3]=o3;
  }
}

// ---------- kernel 3: LN2 + MFMA MLP + residual + NCHW transpose ----------
// 4 waves/block, 64 tokens/block. Wave w owns h-stripe and o-stripe [w*64, w*64+64).
// fc1 streamed in 4 h-chunks of 256; fc2 accumulates across chunks in 64 VGPRs.
// Weights pre-packed in fragment order (k_fragw) -> B-frag load = coalesced 1KB/wave.
__global__ __launch_bounds__(256, 2) void k_mlp(
    const float* __restrict__ zt,
    const float* __restrict__ g2, const float* __restrict__ b2,
    const unsigned short* __restrict__ w1f, const float* __restrict__ fc1b,
    const unsigned short* __restrict__ w2f, const float* __restrict__ fc2b,
    float* __restrict__ out)
{
  __shared__ __align__(16) unsigned short smu[2*64*264];
  unsigned short* ztn  = smu;            // [64][264] bf16 LN2(x)
  unsigned short* hbuf = smu + 64*264;   // [64][264] bf16 gelu(fc1) chunk
  float* ob = (float*)smu;               // [64][257] f32 (reused at end)

  const int tid  = threadIdx.x;
  const int mB   = blockIdx.x << 6;
  const int lane = tid & 63, wave = tid >> 6;
  const int col  = lane & 15, quad = lane >> 4;

  { // LN2: 4 threads per token
    const int tok = tid >> 2, qd = tid & 3;
    const float* zr = zt + (size_t)(mB+tok)*256 + qd*64;
    float v[64];
    #pragma unroll
    for (int j4=0;j4<16;++j4){
      float4 t = ((const float4*)zr)[j4];
      v[j4*4+0]=t.x; v[j4*4+1]=t.y; v[j4*4+2]=t.z; v[j4*4+3]=t.w;
    }
    float s=0.f, q=0.f;
    #pragma unroll
    for (int j=0;j<64;++j){ s += v[j]; q += v[j]*v[j]; }
    s += __shfl_xor(s,1); q += __shfl_xor(q,1);
    s += __shfl_xor(s,2); q += __shfl_xor(q,2);
    float mean = s*(1.f/256.f);
    float rstd = rsqrtf(q*(1.f/256.f) - mean*mean + 1e-5f);
    float gv[64], bv[64];
    #pragma unroll
    for (int j4=0;j4<16;++j4){
      float4 t = ((const float4*)(g2 + qd*64))[j4];
      gv[j4*4+0]=t.x; gv[j4*4+1]=t.y; gv[j4*4+2]=t.z; gv[j4*4+3]=t.w;
      float4 u = ((const float4*)(b2 + qd*64))[j4];
      bv[j4*4+0]=u.x; bv[j4*4+1]=u.y; bv[j4*4+2]=u.z; bv[j4*4+3]=u.w;
    }
    unsigned short* zd = ztn + tok*264 + qd*64;
    #pragma unroll
    for (int j8=0;j8<8;++j8){
      float r[8];
      #pragma unroll
      for (int e=0;e<8;++e) r[e] = (v[j8*8+e]-mean)*rstd*gv[j8*8+e] + bv[j8*8+e];
      uint4 u;
      u.x=pk2(r[0],r[1]); u.y=pk2(r[2],r[3]); u.z=pk2(r[4],r[5]); u.w=pk2(r[6],r[7]);
      *(uint4*)(zd + j8*8) = u;
    }
  }
  __syncthreads();

  floatx4 oacc[4][4];   // [mtile][otile]
  #pragma unroll
  for (int i=0;i<4;++i)
    #pragma unroll
    for (int j=0;j<4;++j) oacc[i][j] = (floatx4){0.f,0.f,0.f,0.f};

  #pragma unroll 1
  for (int hb=0; hb<4; ++hb){
    // ---- fc1: H[:, hb*256 + wave*64 .. +63] ----
    float bv1[4];
    #pragma unroll
    for (int nt=0;nt<4;++nt) bv1[nt] = fc1b[hb*256 + wave*64 + nt*16 + col];
    #pragma unroll 1
    for (int mt=0; mt<4; ++mt){
      floatx4 hacc[4];
      #pragma unroll
      for (int nt=0;nt<4;++nt) hacc[nt] = (floatx4){0.f,0.f,0.f,0.f};
      #pragma unroll
      for (int ks=0; ks<8; ++ks){
        bhalf8 a = *(const bhalf8*)(ztn + (mt*16 + col)*264 + ks*32 + (quad<<3));
        #pragma unroll
        for (int nt=0; nt<4; ++nt){
          int gnt = hb*16 + wave*4 + nt;
          bhalf8 b = *(const bhalf8*)(w1f + (size_t)((gnt*8 + ks)*64 + lane)*8);
          hacc[nt] = __builtin_amdgcn_mfma_f32_16x16x32_bf16(a, b, hacc[nt], 0, 0, 0);
        }
      }
      #pragma unroll
      for (int nt=0; nt<4; ++nt){
        int ch = wave*64 + nt*16 + col;
        #pragma unroll
        for (int r=0;r<4;++r){
          float x = hacc[nt][r] + bv1[nt];
          hbuf[(mt*16 + quad*4 + r)*264 + ch] = f2bf(gelu(x));
        }
      }
    }
    __syncthreads();
    // ---- fc2: oacc += H_chunk @ W2^T (o-stripe = wave*64..+63) ----
    #pragma unroll 1
    for (int mt=0; mt<4; ++mt){
      #pragma unroll
      for (int ks=0; ks<8; ++ks){
        bhalf8 a = *(const bhalf8*)(hbuf + (mt*16 + col)*264 + ks*32 + (quad<<3));
        #pragma unroll
        for (int ot=0; ot<4; ++ot){
          int go = wave*4 + ot;
          bhalf8 b = *(const bhalf8*)(w2f + (size_t)((go*32 + hb*8 + ks)*64 + lane)*8);
          oacc[mt][ot] = __builtin_amdgcn_mfma_f32_16x16x32_bf16(a, b, oacc[mt][ot], 0, 0, 0);
        }
      }
    }
    __syncthreads();
  }

  // ---- epilogue: bias + residual -> ob (padded), then coalesced NCHW write ----
  #pragma unroll
  for (int ot=0; ot<4; ++ot){
    int o = wave*64 + ot*16 + col;
    float bo = fc2b[o];
    #pragma unroll
    for (int mt=0; mt<4; ++mt){
      #pragma unroll
      for (int r=0;r<4;++r){
        int tok = mt*16 + quad*4 + r;
        float zv = zt[(size_t)(mB+tok)*256 + o];
        ob[tok*257 + o] = oacc[mt][ot][r] + bo + zv;
      }
    }
  }
  __syncthreads();
  {
    const int b = mB >> 14, hw0 = mB & 16383;
    float* obase = out + (size_t)b*(256*16384) + hw0;
    #pragma unroll 1
    for (int it=0; it<64; ++it){
      int l = it*256 + tid;
      int o = l >> 6, tk = l & 63;
      obase[(size_t)o*16384 + tk] = ob[tk*257 + o];
    }
  }
}

// ---------- host ----------
extern "C" void kernel_launch(void* const* d_in, const int* in_sizes, int n_in,
                              void* d_out, int out_size, void* d_ws, size_t ws_size,
                              hipStream_t stream)
{
  (void)in_sizes; (void)n_in; (void)out_size; (void)ws_size;
  const float* LH    = (const float*)d_in[0];
  const float* HL    = (const float*)d_in[1];
  const float* HH    = (const float*)d_in[2];
  const float* Spat  = (const float*)d_in[3];
  const float* w_hllh= (const float*)d_in[4];
  const float* b_hllh= (const float*)d_in[5];
  const float* w_hh  = (const float*)d_in[6];
  const float* b_hh  = (const float*)d_in[7];
  const float* w_spat= (const float*)d_in[8];
  const float* b_spat= (const float*)d_in[9];
  const float* ln1x_g= (const float*)d_in[10];
  const float* ln1x_b= (const float*)d_in[11];
  const float* ln1y_g= (const float*)d_in[12];
  const float* ln1y_b= (const float*)d_in[13];
  const float* qkv_w = (const float*)d_in[14];
  const float* qkv_b = (const float*)d_in[15];
  const float* qkv2_w= (const float*)d_in[16];
  const float* qkv2_b= (const float*)d_in[17];
  const float* qkv3_w= (const float*)d_in[18];
  const float* qkv3_b= (const float*)d_in[19];
  const float* proj_w= (const float*)d_in[20];
  const float* proj_b= (const float*)d_in[21];
  const float* rpb   = (const float*)d_in[22];
  const float* ln2_g = (const float*)d_in[23];
  const float* ln2_b = (const float*)d_in[24];
  const float* fc1_w = (const float*)d_in[25];
  const float* fc1_b = (const float*)d_in[26];
  const float* fc2_w = (const float*)d_in[27];
  const float* fc2_b = (const float*)d_in[28];
  float* out = (float*)d_out;

  char* ws = (char*)d_ws;
  size_t off = 0;
  auto alloc = [&](size_t bytes)->void*{
    void* p = ws + off; off += (bytes + 255) & ~(size_t)255; return p;
  };
  const size_t M = 131072;
  unsigned short* xn = (unsigned short*)alloc(M*256*2);
  unsigned short* yn = (unsigned short*)alloc(M*256*2);
  unsigned short* z0 = (unsigned short*)alloc(M*256*2);
  float* zt  = (float*)alloc(M*256*4);
  float* wtx = (float*)alloc(128*256*4);
  float* wtz = (float*)alloc(64*256*4);
  float* wty = (float*)alloc(64*256*4);
  float* wqt = (float*)alloc(256*256*4);
  float* wkt = (float*)alloc(256*256*4);
  float* wvt = (float*)alloc(256*256*4);
  float* wpt = (float*)alloc(256*256*4);
  unsigned short* w1f = (unsigned short*)alloc(1024*256*2);
  unsigned short* w2f = (unsigned short*)alloc(256*1024*2);
  float* bqs = (float*)alloc(256*4);

  const float sc = 0.17677669529663687f;  // 1/sqrt(hd=32), folded into q weights+bias
  k_transpose_f32<<<dim3(128),  dim3(256), 0, stream>>>(w_hllh, wtx, 256, 128, 1.f);
  k_transpose_f32<<<dim3(64),   dim3(256), 0, stream>>>(w_hh,   wtz, 256, 64, 1.f);
  k_transpose_f32<<<dim3(64),   dim3(256), 0, stream>>>(w_spat, wty, 256, 64, 1.f);
  k_transpose_f32<<<dim3(256),  dim3(256), 0, stream>>>(qkv_w,  wqt, 256, 256, sc);
  k_transpose_f32<<<dim3(256),  dim3(256), 0, stream>>>(qkv2_w, wkt, 256, 256, 1.f);
  k_transpose_f32<<<dim3(256),  dim3(256), 0, stream>>>(qkv3_w, wvt, 256, 256, 1.f);
  k_transpose_f32<<<dim3(256),  dim3(256), 0, stream>>>(proj_w, wpt, 256, 256, 1.f);
  k_fragw       <<<dim3(1024), dim3(256), 0, stream>>>(fc1_w, w1f, 1024*256, 256);
  k_fragw       <<<dim3(1024), dim3(256), 0, stream>>>(fc2_w, w2f, 256*1024, 1024);
  k_scale_vec   <<<dim3(1),    dim3(256), 0, stream>>>(qkv_b, bqs, 256, sc);

  k_conv_ln<<<dim3(2048), dim3(256), 0, stream>>>(LH, HL, HH, Spat,
      wtx, b_hllh, wtz, b_hh, wty, b_spat,
      ln1x_g, ln1x_b, ln1y_g, ln1y_b, xn, yn, z0);
  k_attn<<<dim3(2048), dim3(256), 0, stream>>>(xn, yn, z0,
      wqt, bqs, wkt, qkv2_b, wvt, qkv3_b, wpt, proj_b, rpb, zt);
  k_mlp<<<dim3(2048), dim3(256), 0, stream>>>(zt, ln2_g, ln2_b,
      w1f, fc1_b, w2f, fc2_b, out);
}

// Round 3
// 1304.894 us; speedup vs baseline: 4.1528x; 2.2666x over previous
//
#include <hip/hip_runtime.h>
#include <math.h>

#define DI static __device__ __forceinline__

typedef __attribute__((ext_vector_type(8))) short bhalf8;
typedef __attribute__((ext_vector_type(4))) float floatx4;

// ---------- bf16 helpers ----------
DI unsigned short f2bf(float f){
  union { float f; unsigned u; } v; v.f = f;
  unsigned r = (v.u + 0x7fffu + ((v.u >> 16) & 1u)) >> 16;
  return (unsigned short)r;
}
DI float bflo(unsigned v){ return __uint_as_float(v << 16); }
DI float bfhi(unsigned v){ return __uint_as_float(v & 0xffff0000u); }
DI unsigned pk2(float a, float b){ return (unsigned)f2bf(a) | ((unsigned)f2bf(b) << 16); }
DI void unpack8(uint4 u, float* a){
  a[0]=bflo(u.x); a[1]=bfhi(u.x); a[2]=bflo(u.y); a[3]=bfhi(u.y);
  a[4]=bflo(u.z); a[5]=bfhi(u.z); a[6]=bflo(u.w); a[7]=bfhi(u.w);
}
DI void load16(const float* p, float* v){
  const float4* q = (const float4*)p;
  float4 a=q[0], b=q[1], c=q[2], d=q[3];
  v[0]=a.x; v[1]=a.y; v[2]=a.z; v[3]=a.w;
  v[4]=b.x; v[5]=b.y; v[6]=b.z; v[7]=b.w;
  v[8]=c.x; v[9]=c.y; v[10]=c.z; v[11]=c.w;
  v[12]=d.x; v[13]=d.y; v[14]=d.z; v[15]=d.w;
}
DI void store16bf(unsigned short* p, const float* r){
  uint4 u0, u1;
  u0.x=pk2(r[0],r[1]);  u0.y=pk2(r[2],r[3]);  u0.z=pk2(r[4],r[5]);  u0.w=pk2(r[6],r[7]);
  u1.x=pk2(r[8],r[9]);  u1.y=pk2(r[10],r[11]); u1.z=pk2(r[12],r[13]); u1.w=pk2(r[14],r[15]);
  *(uint4*)p = u0; *(uint4*)(p+8) = u1;
}
// tanh-form GELU: max |err| vs exact ~3e-4
DI float gelu(float x){
  float u = x*(0.7978845608f + 0.0356774081f*x*x);
  float e = __expf(2.f*u);
  return x - x/(e + 1.f);
}

// ---------- prep kernels ----------
__global__ void k_transpose_f32(const float* __restrict__ src, float* __restrict__ dst,
                                int O, int K, float scale){
  int idx = blockIdx.x * 256 + threadIdx.x;
  if (idx >= O*K) return;
  int o = idx / K, k = idx - o*K;
  dst[k*O + o] = src[idx] * scale;
}
__global__ void k_scale_vec(const float* __restrict__ src, float* __restrict__ dst, int n, float s){
  int i = blockIdx.x*256 + threadIdx.x;
  if (i < n) dst[i] = src[i]*s;
}
// pack weight (O x K f32 row-major) into bf16 MFMA B-fragment order
__global__ void k_fragw(const float* __restrict__ src, unsigned short* __restrict__ dst,
                        int n, int K, float scale){
  int t = blockIdx.x*256 + threadIdx.x;
  if (t >= n) return;
  int j = t & 7, lane = (t >> 3) & 63, rest = t >> 9;
  int KS = K >> 5;
  int ks = rest % KS, nt = rest / KS;
  int row = nt*16 + (lane & 15);
  int col = ks*32 + ((lane >> 4) << 3) + j;
  dst[t] = f2bf(src[(size_t)row*K + col] * scale);
}
// relative-position bias in C-fragment layout: biasf[((h*4+mt)*4+nt)*256 + lane*4 + r]
__global__ void k_bias(const float* __restrict__ rpb, float* __restrict__ biasf){
  int t = blockIdx.x*256 + threadIdx.x;   // 32768 total
  int r = t & 3, lane = (t>>2) & 63, nt = (t>>8) & 3, mt = (t>>10) & 3, h = t>>12;
  int qtok = mt*16 + (lane>>4)*4 + r;
  int ktok = nt*16 + (lane & 15);
  int idx = ((qtok>>3) - (ktok>>3) + 7)*15 + ((qtok&7) - (ktok&7) + 7);
  biasf[t] = rpb[idx*8 + h];
}

// ---------- kernel 1: conv + LN1 (fp32 VALU) fused with QKV MFMA GEMMs ----------
// block = 64 consecutive raster tokens (half an image row -> 8 windows, one tok-row each).
// xn/yn live only in LDS. Outputs: z0 (bf16 token-major), q/k (bf16 window-major row-major),
// vt (bf16 window-major transposed [win][ch][tok]).
__global__ __launch_bounds__(256) void k_front(
    const float* __restrict__ LH, const float* __restrict__ HL,
    const float* __restrict__ HH, const float* __restrict__ Sp,
    const float* __restrict__ wtx, const float* __restrict__ bx,
    const float* __restrict__ wtz, const float* __restrict__ bz,
    const float* __restrict__ wty, const float* __restrict__ by,
    const float* __restrict__ g1x, const float* __restrict__ b1x,
    const float* __restrict__ g1y, const float* __restrict__ b1y,
    const unsigned short* __restrict__ wqf, const float* __restrict__ bq,
    const unsigned short* __restrict__ wkf, const float* __restrict__ bk,
    const unsigned short* __restrict__ wvf, const float* __restrict__ bv,
    unsigned short* __restrict__ z0, unsigned short* __restrict__ qg,
    unsigned short* __restrict__ kg, unsigned short* __restrict__ vtg)
{
  __shared__ __align__(16) unsigned short sbufA[64*288];  // xn [64][264] -> staging [64][264] / vtb [256][72]
  __shared__ __align__(16) unsigned short sbufB[64*264];  // yn [64][264]
  __shared__ float part[16][64][2];
  __shared__ float stats[64][2];

  const int tid = threadIdx.x;
  const int tt = tid & 15, oo = tid >> 4;
  const int lane = tid & 63, wave = tid >> 6, col = lane & 15, quad = lane >> 4;
  const int mB = blockIdx.x << 6;
  const int b  = mB >> 14;
  const int p0 = mB & 16383;
  const int hrow = p0 >> 7, w0 = p0 & 127;
  const int winb = b*256 + (hrow>>3)*16 + (w0>>3);
  const int tokrow = (hrow & 7)*8;
  const size_t pb = (size_t)b * (64*16384) + p0 + tt*4;

  float acc[4][16];
  auto zero_acc = [&](){
    #pragma unroll
    for (int i=0;i<4;++i)
      #pragma unroll
      for (int j=0;j<16;++j) acc[i][j] = 0.f;
  };
  auto accum64 = [&](const float* plane, const float* wt, int c0){
    #pragma unroll 2
    for (int c=0;c<64;++c){
      float4 a4 = *(const float4*)(plane + (size_t)c*16384);
      float wv[16]; load16(wt + (c0+c)*256 + oo*16, wv);
      float av[4] = {a4.x, a4.y, a4.z, a4.w};
      #pragma unroll
      for (int i=0;i<4;++i)
        #pragma unroll
        for (int j=0;j<16;++j) acc[i][j] += av[i]*wv[j];
    }
  };
  auto ln_lds = [&](const float* bias, const float* g, const float* bb,
                    unsigned short* dst){
    float bvv[16]; load16(bias + oo*16, bvv);
    #pragma unroll
    for (int i=0;i<4;++i){
      float s=0.f, q=0.f;
      #pragma unroll
      for (int j=0;j<16;++j){ float v = acc[i][j]+bvv[j]; acc[i][j]=v; s+=v; q+=v*v; }
      part[oo][tt*4+i][0]=s; part[oo][tt*4+i][1]=q;
    }
    __syncthreads();
    if (tid < 64){
      float s=0.f, q=0.f;
      #pragma unroll
      for (int gi=0;gi<16;++gi){ s += part[gi][tid][0]; q += part[gi][tid][1]; }
      float mean = s*(1.f/256.f);
      float var  = q*(1.f/256.f) - mean*mean;
      stats[tid][0]=mean;
      stats[tid][1]=rsqrtf(var + 1e-5f);
    }
    __syncthreads();
    float gv[16], av2[16];
    load16(g + oo*16, gv); load16(bb + oo*16, av2);
    #pragma unroll
    for (int i=0;i<4;++i){
      int tok = tt*4+i;
      float mean = stats[tok][0], rstd = stats[tok][1];
      float r[16];
      #pragma unroll
      for (int j=0;j<16;++j) r[j] = (acc[i][j]-mean)*rstd*gv[j] + av2[j];
      store16bf(dst + tok*264 + oo*16, r);
    }
    __syncthreads();
  };

  // conv x -> LN1x -> sbufA ; conv y -> LN1y -> sbufB ; conv z0 -> global
  zero_acc(); accum64(LH + pb, wtx, 0); accum64(HL + pb, wtx, 64);
  ln_lds(bx, g1x, b1x, sbufA);
  zero_acc(); accum64(Sp + pb, wty, 0);
  ln_lds(by, g1y, b1y, sbufB);
  zero_acc(); accum64(HH + pb, wtz, 0);
  {
    float bvv[16]; load16(bz + oo*16, bvv);
    #pragma unroll
    for (int i=0;i<4;++i){
      int tok = tt*4+i;
      float r[16];
      #pragma unroll
      for (int j=0;j<16;++j) r[j] = acc[i][j] + bvv[j];
      store16bf(z0 + (size_t)(mB+tok)*256 + oo*16, r);
    }
  }
  __syncthreads();

  // ---- QKV MFMA GEMMs: wave owns out-ch stripe [wave*64, wave*64+64) ----
  auto gemm = [&](const unsigned short* Abuf, const unsigned short* wf,
                  const float* bias, floatx4 (&c)[4][4]){
    #pragma unroll
    for (int mt=0;mt<4;++mt)
      #pragma unroll
      for (int nt=0;nt<4;++nt) c[mt][nt] = (floatx4){0.f,0.f,0.f,0.f};
    #pragma unroll
    for (int ks=0; ks<8; ++ks){
      bhalf8 a[4];
      #pragma unroll
      for (int mt=0;mt<4;++mt)
        a[mt] = *(const bhalf8*)(Abuf + (mt*16+col)*264 + ks*32 + (quad<<3));
      #pragma unroll
      for (int nt=0;nt<4;++nt){
        bhalf8 bf = *(const bhalf8*)(wf + (size_t)(((wave*4+nt)*8 + ks)*64 + lane)*8);
        #pragma unroll
        for (int mt=0;mt<4;++mt)
          c[mt][nt] = __builtin_amdgcn_mfma_f32_16x16x32_bf16(a[mt], bf, c[mt][nt], 0, 0, 0);
      }
    }
    #pragma unroll
    for (int nt=0;nt<4;++nt){
      float bb2 = bias[wave*64 + nt*16 + col];
      #pragma unroll
      for (int mt=0;mt<4;++mt)
        #pragma unroll
        for (int r=0;r<4;++r) c[mt][nt][r] += bb2;
    }
  };
  auto stage_write = [&](floatx4 (&c)[4][4], unsigned short* gout){
    __syncthreads();   // prior readers of sbufA done
    #pragma unroll
    for (int mt=0;mt<4;++mt)
      #pragma unroll
      for (int nt=0;nt<4;++nt)
        #pragma unroll
        for (int r=0;r<4;++r)
          sbufA[(mt*16+quad*4+r)*264 + wave*64 + nt*16 + col] = f2bf(c[mt][nt][r]);
    __syncthreads();
    int tok = tid >> 2, c0 = (tid & 3)*64;
    const uint4* s = (const uint4*)(sbufA + tok*264 + c0);
    uint4* d = (uint4*)(gout + ((size_t)(winb + (tok>>3)))*16384 + (size_t)(tokrow + (tok&7))*256 + c0);
    #pragma unroll
    for (int i=0;i<8;++i) d[i] = s[i];
  };

  floatx4 c[4][4];
  gemm(sbufA, wqf, bq, c);
  stage_write(c, qg);
  gemm(sbufB, wkf, bk, c);
  stage_write(c, kg);
  gemm(sbufB, wvf, bv, c);
  // vt: transposed staging [256 ch][72] then per-window uint4 writes
  __syncthreads();
  #pragma unroll
  for (int mt=0;mt<4;++mt)
    #pragma unroll
    for (int nt=0;nt<4;++nt){
      int ch = wave*64 + nt*16 + col;
      uint2 u; u.x = pk2(c[mt][nt][0], c[mt][nt][1]); u.y = pk2(c[mt][nt][2], c[mt][nt][3]);
      *(uint2*)(sbufA + ch*72 + mt*16 + quad*4) = u;
    }
  __syncthreads();
  {
    int ch = tid;
    #pragma unroll
    for (int wi=0; wi<8; ++wi){
      uint4 val = *(const uint4*)(sbufA + ch*72 + wi*8);
      *(uint4*)(vtg + ((size_t)(winb + wi))*16384 + ch*64 + tokrow) = val;
    }
  }
}

// ---------- kernel 2: MFMA window attention ----------
// block = 1 window, 4 waves, wave = heads {2w, 2w+1}. Exact softmax in registers,
// P round-trips through wave-private LDS (C-layout -> A-layout), 1/l folded into O.
__global__ __launch_bounds__(256, 2) void k_attn2(
    const unsigned short* __restrict__ qg, const unsigned short* __restrict__ kg,
    const unsigned short* __restrict__ vtg, const float* __restrict__ biasf,
    unsigned short* __restrict__ attnout)
{
  __shared__ __align__(16) unsigned short Pb[4*64*72];
  __shared__ __align__(16) unsigned short Ob[64*264];
  const int tid = threadIdx.x, lane = tid & 63, wave = tid >> 6;
  const int col = lane & 15, quad = lane >> 4;
  const size_t wbase = (size_t)blockIdx.x * 16384;
  const unsigned short* qw = qg + wbase;
  const unsigned short* kw = kg + wbase;
  const unsigned short* vw = vtg + wbase;
  unsigned short* Pw = Pb + wave*64*72;

  #pragma unroll 1
  for (int hh=0; hh<2; ++hh){
    const int h = wave*2 + hh;
    bhalf8 qf[4], kf[4];
    #pragma unroll
    for (int mt=0;mt<4;++mt)
      qf[mt] = *(const bhalf8*)(qw + (mt*16+col)*256 + h*32 + (quad<<3));
    #pragma unroll
    for (int nt=0;nt<4;++nt)
      kf[nt] = *(const bhalf8*)(kw + (nt*16+col)*256 + h*32 + (quad<<3));
    floatx4 S[4][4];
    #pragma unroll
    for (int mt=0;mt<4;++mt)
      #pragma unroll
      for (int nt=0;nt<4;++nt) S[mt][nt] = (floatx4){0.f,0.f,0.f,0.f};
    #pragma unroll
    for (int mt=0;mt<4;++mt)
      #pragma unroll
      for (int nt=0;nt<4;++nt)
        S[mt][nt] = __builtin_amdgcn_mfma_f32_16x16x32_bf16(qf[mt], kf[nt], S[mt][nt], 0, 0, 0);
    // + relative position bias (C-fragment layout, coalesced float4)
    #pragma unroll
    for (int mt=0;mt<4;++mt)
      #pragma unroll
      for (int nt=0;nt<4;++nt){
        float4 bb = *(const float4*)(biasf + (size_t)(((h*4+mt)*4+nt))*256 + lane*4);
        S[mt][nt][0] += bb.x; S[mt][nt][1] += bb.y; S[mt][nt][2] += bb.z; S[mt][nt][3] += bb.w;
      }
    // softmax over 64 keys: local max/sum over nt, 16-lane shuffle reduce within quad-row
    float linv[4][4];
    #pragma unroll
    for (int mt=0;mt<4;++mt){
      #pragma unroll
      for (int r=0;r<4;++r){
        float mx = fmaxf(fmaxf(S[mt][0][r], S[mt][1][r]), fmaxf(S[mt][2][r], S[mt][3][r]));
        mx = fmaxf(mx, __shfl_xor(mx, 1));
        mx = fmaxf(mx, __shfl_xor(mx, 2));
        mx = fmaxf(mx, __shfl_xor(mx, 4));
        mx = fmaxf(mx, __shfl_xor(mx, 8));
        float e0 = __expf(S[mt][0][r]-mx), e1 = __expf(S[mt][1][r]-mx);
        float e2 = __expf(S[mt][2][r]-mx), e3 = __expf(S[mt][3][r]-mx);
        S[mt][0][r]=e0; S[mt][1][r]=e1; S[mt][2][r]=e2; S[mt][3][r]=e3;
        float l = e0+e1+e2+e3;
        l += __shfl_xor(l, 1);
        l += __shfl_xor(l, 2);
        l += __shfl_xor(l, 4);
        l += __shfl_xor(l, 8);
        linv[mt][r] = 1.f/l;
      }
    }
    // P: C-layout scatter into wave-private LDS (bf16)
    #pragma unroll
    for (int mt=0;mt<4;++mt)
      #pragma unroll
      for (int nt=0;nt<4;++nt)
        #pragma unroll
        for (int r=0;r<4;++r)
          Pw[(mt*16+quad*4+r)*72 + nt*16 + col] = f2bf(S[mt][nt][r]);
    asm volatile("s_waitcnt lgkmcnt(0)" ::: "memory");
    // PV: A = P (LDS b128), B = V^T (global b128)
    floatx4 O[4][2];
    #pragma unroll
    for (int mt=0;mt<4;++mt){ O[mt][0]=(floatx4){0.f,0.f,0.f,0.f}; O[mt][1]=(floatx4){0.f,0.f,0.f,0.f}; }
    #pragma unroll
    for (int ks=0; ks<2; ++ks){
      bhalf8 vf[2];
      #pragma unroll
      for (int nt2=0;nt2<2;++nt2)
        vf[nt2] = *(const bhalf8*)(vw + (h*32 + nt2*16 + col)*64 + ks*32 + (quad<<3));
      #pragma unroll
      for (int mt=0;mt<4;++mt){
        bhalf8 pf = *(const bhalf8*)(Pw + (mt*16+col)*72 + ks*32 + (quad<<3));
        #pragma unroll
        for (int nt2=0;nt2<2;++nt2)
          O[mt][nt2] = __builtin_amdgcn_mfma_f32_16x16x32_bf16(pf, vf[nt2], O[mt][nt2], 0, 0, 0);
      }
    }
    // O scaled by 1/l -> shared O buffer (bf16 row-major)
    #pragma unroll
    for (int mt=0;mt<4;++mt)
      #pragma unroll
      for (int nt2=0;nt2<2;++nt2)
        #pragma unroll
        for (int r=0;r<4;++r)
          Ob[(mt*16+quad*4+r)*264 + h*32 + nt2*16 + col] = f2bf(O[mt][nt2][r]*linv[mt][r]);
  }
  __syncthreads();
  {
    int tok = tid >> 2, c0 = (tid & 3)*64;
    const uint4* s = (const uint4*)(Ob + tok*264 + c0);
    uint4* d = (uint4*)(attnout + wbase + tok*256 + c0);
    #pragma unroll
    for (int i=0;i<8;++i) d[i] = s[i];
  }
}

// ---------- kernel 3: proj GEMM + z0 residual -> zt (f32 token-major) ----------
__global__ __launch_bounds__(256) void k_proj(
    const unsigned short* __restrict__ attnout, const unsigned short* __restrict__ wpf,
    const float* __restrict__ bp, const unsigned short* __restrict__ z0,
    float* __restrict__ zt)
{
  __shared__ __align__(16) unsigned short inbuf[64*264];
  __shared__ __align__(16) float obuf[32*260];
  const int tid = threadIdx.x, lane = tid & 63, wave = tid >> 6;
  const int col = lane & 15, quad = lane >> 4;
  const int win = blockIdx.x;
  const int b = win >> 8, whi = (win >> 4) & 15, wwi = win & 15;

  {
    int tok = tid >> 2, c0 = (tid & 3)*64;
    const uint4* s = (const uint4*)(attnout + (size_t)win*16384 + tok*256 + c0);
    uint4* d = (uint4*)(inbuf + tok*264 + c0);
    #pragma unroll
    for (int i=0;i<8;++i) d[i] = s[i];
  }
  __syncthreads();

  floatx4 c[4][4];
  #pragma unroll
  for (int mt=0;mt<4;++mt)
    #pragma unroll
    for (int nt=0;nt<4;++nt) c[mt][nt] = (floatx4){0.f,0.f,0.f,0.f};
  #pragma unroll
  for (int ks=0; ks<8; ++ks){
    bhalf8 a[4];
    #pragma unroll
    for (int mt=0;mt<4;++mt)
      a[mt] = *(const bhalf8*)(inbuf + (mt*16+col)*264 + ks*32 + (quad<<3));
    #pragma unroll
    for (int nt=0;nt<4;++nt){
      bhalf8 bf = *(const bhalf8*)(wpf + (size_t)(((wave*4+nt)*8 + ks)*64 + lane)*8);
      #pragma unroll
      for (int mt=0;mt<4;++mt)
        c[mt][nt] = __builtin_amdgcn_mfma_f32_16x16x32_bf16(a[mt], bf, c[mt][nt], 0, 0, 0);
    }
  }
  float bb[4];
  #pragma unroll
  for (int nt=0;nt<4;++nt) bb[nt] = bp[wave*64 + nt*16 + col];

  #pragma unroll 1
  for (int p=0; p<2; ++p){
    __syncthreads();
    #pragma unroll
    for (int mt2=0;mt2<2;++mt2){
      int mt = p*2 + mt2;
      #pragma unroll
      for (int nt=0;nt<4;++nt)
        #pragma unroll
        for (int r=0;r<4;++r)
          obuf[(mt2*16+quad*4+r)*260 + wave*64 + nt*16 + col] = c[mt][nt][r] + bb[nt];
    }
    __syncthreads();
    {
      int tl = tid >> 3, c0 = (tid & 7)*32;
      int tok = p*32 + tl;
      int hh = whi*8 + (tok>>3), ww = wwi*8 + (tok&7);
      size_t rast = (size_t)b*16384 + hh*128 + ww;
      const float4* s = (const float4*)(obuf + tl*260 + c0);
      const uint4* zp = (const uint4*)(z0 + rast*256 + c0);
      float zv[32];
      #pragma unroll
      for (int i=0;i<4;++i) unpack8(zp[i], zv + i*8);
      float4* d = (float4*)(zt + rast*256 + c0);
      #pragma unroll
      for (int i=0;i<8;++i){
        float4 o = s[i];
        o.x += zv[i*4+0]; o.y += zv[i*4+1]; o.z += zv[i*4+2]; o.w += zv[i*4+3];
        d[i] = o;
      }
    }
  }
}

// ---------- kernel 4: LN2 + MFMA MLP + residual + NCHW transpose (unchanged) ----------
__global__ __launch_bounds__(256, 2) void k_mlp(
    const float* __restrict__ zt,
    const float* __restrict__ g2, const float* __restrict__ b2,
    const unsigned short* __restrict__ w1f, const float* __restrict__ fc1b,
    const unsigned short* __restrict__ w2f, const float* __restrict__ fc2b,
    float* __restrict__ out)
{
  __shared__ __align__(16) unsigned short smu[2*64*264];
  unsigned short* ztn  = smu;
  unsigned short* hbuf = smu + 64*264;
  float* ob = (float*)smu;

  const int tid  = threadIdx.x;
  const int mB   = blockIdx.x << 6;
  const int lane = tid & 63, wave = tid >> 6;
  const int col  = lane & 15, quad = lane >> 4;

  {
    const int tok = tid >> 2, qd = tid & 3;
    const float* zr = zt + (size_t)(mB+tok)*256 + qd*64;
    float v[64];
    #pragma unroll
    for (int j4=0;j4<16;++j4){
      float4 t = ((const float4*)zr)[j4];
      v[j4*4+0]=t.x; v[j4*4+1]=t.y; v[j4*4+2]=t.z; v[j4*4+3]=t.w;
    }
    float s=0.f, q=0.f;
    #pragma unroll
    for (int j=0;j<64;++j){ s += v[j]; q += v[j]*v[j]; }
    s += __shfl_xor(s,1); q += __shfl_xor(q,1);
    s += __shfl_xor(s,2); q += __shfl_xor(q,2);
    float mean = s*(1.f/256.f);
    float rstd = rsqrtf(q*(1.f/256.f) - mean*mean + 1e-5f);
    float gv[64], bv[64];
    #pragma unroll
    for (int j4=0;j4<16;++j4){
      float4 t = ((const float4*)(g2 + qd*64))[j4];
      gv[j4*4+0]=t.x; gv[j4*4+1]=t.y; gv[j4*4+2]=t.z; gv[j4*4+3]=t.w;
      float4 u = ((const float4*)(b2 + qd*64))[j4];
      bv[j4*4+0]=u.x; bv[j4*4+1]=u.y; bv[j4*4+2]=u.z; bv[j4*4+3]=u.w;
    }
    unsigned short* zd = ztn + tok*264 + qd*64;
    #pragma unroll
    for (int j8=0;j8<8;++j8){
      float r[8];
      #pragma unroll
      for (int e=0;e<8;++e) r[e] = (v[j8*8+e]-mean)*rstd*gv[j8*8+e] + bv[j8*8+e];
      uint4 u;
      u.x=pk2(r[0],r[1]); u.y=pk2(r[2],r[3]); u.z=pk2(r[4],r[5]); u.w=pk2(r[6],r[7]);
      *(uint4*)(zd + j8*8) = u;
    }
  }
  __syncthreads();

  floatx4 oacc[4][4];
  #pragma unroll
  for (int i=0;i<4;++i)
    #pragma unroll
    for (int j=0;j<4;++j) oacc[i][j] = (floatx4){0.f,0.f,0.f,0.f};

  #pragma unroll 1
  for (int hb=0; hb<4; ++hb){
    float bv1[4];
    #pragma unroll
    for (int nt=0;nt<4;++nt) bv1[nt] = fc1b[hb*256 + wave*64 + nt*16 + col];
    #pragma unroll 1
    for (int mt=0; mt<4; ++mt){
      floatx4 hacc[4];
      #pragma unroll
      for (int nt=0;nt<4;++nt) hacc[nt] = (floatx4){0.f,0.f,0.f,0.f};
      #pragma unroll
      for (int ks=0; ks<8; ++ks){
        bhalf8 a = *(const bhalf8*)(ztn + (mt*16 + col)*264 + ks*32 + (quad<<3));
        #pragma unroll
        for (int nt=0; nt<4; ++nt){
          int gnt = hb*16 + wave*4 + nt;
          bhalf8 b = *(const bhalf8*)(w1f + (size_t)((gnt*8 + ks)*64 + lane)*8);
          hacc[nt] = __builtin_amdgcn_mfma_f32_16x16x32_bf16(a, b, hacc[nt], 0, 0, 0);
        }
      }
      #pragma unroll
      for (int nt=0; nt<4; ++nt){
        int ch = wave*64 + nt*16 + col;
        #pragma unroll
        for (int r=0;r<4;++r){
          float x = hacc[nt][r] + bv1[nt];
          hbuf[(mt*16 + quad*4 + r)*264 + ch] = f2bf(gelu(x));
        }
      }
    }
    __syncthreads();
    #pragma unroll 1
    for (int mt=0; mt<4; ++mt){
      #pragma unroll
      for (int ks=0; ks<8; ++ks){
        bhalf8 a = *(const bhalf8*)(hbuf + (mt*16 + col)*264 + ks*32 + (quad<<3));
        #pragma unroll
        for (int ot=0; ot<4; ++ot){
          int go = wave*4 + ot;
          bhalf8 b = *(const bhalf8*)(w2f + (size_t)((go*32 + hb*8 + ks)*64 + lane)*8);
          oacc[mt][ot] = __builtin_amdgcn_mfma_f32_16x16x32_bf16(a, b, oacc[mt][ot], 0, 0, 0);
        }
      }
    }
    __syncthreads();
  }

  #pragma unroll
  for (int ot=0; ot<4; ++ot){
    int o = wave*64 + ot*16 + col;
    float bo = fc2b[o];
    #pragma unroll
    for (int mt=0; mt<4; ++mt){
      #pragma unroll
      for (int r=0;r<4;++r){
        int tok = mt*16 + quad*4 + r;
        float zv = zt[(size_t)(mB+tok)*256 + o];
        ob[tok*257 + o] = oacc[mt][ot][r] + bo + zv;
      }
    }
  }
  __syncthreads();
  {
    const int b = mB >> 14, hw0 = mB & 16383;
    float* obase = out + (size_t)b*(256*16384) + hw0;
    #pragma unroll 1
    for (int it=0; it<64; ++it){
      int l = it*256 + tid;
      int o = l >> 6, tk = l & 63;
      obase[(size_t)o*16384 + tk] = ob[tk*257 + o];
    }
  }
}

// ---------- host ----------
extern "C" void kernel_launch(void* const* d_in, const int* in_sizes, int n_in,
                              void* d_out, int out_size, void* d_ws, size_t ws_size,
                              hipStream_t stream)
{
  (void)in_sizes; (void)n_in; (void)out_size; (void)ws_size;
  const float* LH    = (const float*)d_in[0];
  const float* HL    = (const float*)d_in[1];
  const float* HH    = (const float*)d_in[2];
  const float* Spat  = (const float*)d_in[3];
  const float* w_hllh= (const float*)d_in[4];
  const float* b_hllh= (const float*)d_in[5];
  const float* w_hh  = (const float*)d_in[6];
  const float* b_hh  = (const float*)d_in[7];
  const float* w_spat= (const float*)d_in[8];
  const float* b_spat= (const float*)d_in[9];
  const float* ln1x_g= (const float*)d_in[10];
  const float* ln1x_b= (const float*)d_in[11];
  const float* ln1y_g= (const float*)d_in[12];
  const float* ln1y_b= (const float*)d_in[13];
  const float* qkv_w = (const float*)d_in[14];
  const float* qkv_b = (const float*)d_in[15];
  const float* qkv2_w= (const float*)d_in[16];
  const float* qkv2_b= (const float*)d_in[17];
  const float* qkv3_w= (const float*)d_in[18];
  const float* qkv3_b= (const float*)d_in[19];
  const float* proj_w= (const float*)d_in[20];
  const float* proj_b= (const float*)d_in[21];
  const float* rpb   = (const float*)d_in[22];
  const float* ln2_g = (const float*)d_in[23];
  const float* ln2_b = (const float*)d_in[24];
  const float* fc1_w = (const float*)d_in[25];
  const float* fc1_b = (const float*)d_in[26];
  const float* fc2_w = (const float*)d_in[27];
  const float* fc2_b = (const float*)d_in[28];
  float* out = (float*)d_out;

  char* ws = (char*)d_ws;
  size_t off = 0;
  auto alloc = [&](size_t bytes)->void*{
    void* p = ws + off; off += (bytes + 255) & ~(size_t)255; return p;
  };
  const size_t M = 131072;
  unsigned short* z0  = (unsigned short*)alloc(M*256*2);
  unsigned short* qg  = (unsigned short*)alloc(M*256*2);
  char* kv_region     = (char*)alloc(M*256*4);     // k | vt ; reused as zt (f32)
  unsigned short* kg  = (unsigned short*)kv_region;
  unsigned short* vtg = (unsigned short*)(kv_region + M*256*2);
  float* zt           = (float*)kv_region;
  unsigned short* attnout = (unsigned short*)alloc(M*256*2);
  float* wtx = (float*)alloc(128*256*4);
  float* wtz = (float*)alloc(64*256*4);
  float* wty = (float*)alloc(64*256*4);
  unsigned short* wqf = (unsigned short*)alloc(256*256*2);
  unsigned short* wkf = (unsigned short*)alloc(256*256*2);
  unsigned short* wvf = (unsigned short*)alloc(256*256*2);
  unsigned short* wpf = (unsigned short*)alloc(256*256*2);
  unsigned short* w1f = (unsigned short*)alloc(1024*256*2);
  unsigned short* w2f = (unsigned short*)alloc(256*1024*2);
  float* biasf = (float*)alloc(32768*4);
  float* bqs = (float*)alloc(256*4);

  const float sc = 0.17677669529663687f;  // 1/sqrt(hd=32), folded into q weights+bias
  k_transpose_f32<<<dim3(128),  dim3(256), 0, stream>>>(w_hllh, wtx, 256, 128, 1.f);
  k_transpose_f32<<<dim3(64),   dim3(256), 0, stream>>>(w_hh,   wtz, 256, 64, 1.f);
  k_transpose_f32<<<dim3(64),   dim3(256), 0, stream>>>(w_spat, wty, 256, 64, 1.f);
  k_fragw<<<dim3(256),  dim3(256), 0, stream>>>(qkv_w,  wqf, 256*256, 256, sc);
  k_fragw<<<dim3(256),  dim3(256), 0, stream>>>(qkv2_w, wkf, 256*256, 256, 1.f);
  k_fragw<<<dim3(256),  dim3(256), 0, stream>>>(qkv3_w, wvf, 256*256, 256, 1.f);
  k_fragw<<<dim3(256),  dim3(256), 0, stream>>>(proj_w, wpf, 256*256, 256, 1.f);
  k_fragw<<<dim3(1024), dim3(256), 0, stream>>>(fc1_w,  w1f, 1024*256, 256, 1.f);
  k_fragw<<<dim3(1024), dim3(256), 0, stream>>>(fc2_w,  w2f, 256*1024, 1024, 1.f);
  k_bias <<<dim3(128),  dim3(256), 0, stream>>>(rpb, biasf);
  k_scale_vec<<<dim3(1), dim3(256), 0, stream>>>(qkv_b, bqs, 256, sc);

  k_front<<<dim3(2048), dim3(256), 0, stream>>>(LH, HL, HH, Spat,
      wtx, b_hllh, wtz, b_hh, wty, b_spat,
      ln1x_g, ln1x_b, ln1y_g, ln1y_b,
      wqf, bqs, wkf, qkv2_b, wvf, qkv3_b,
      z0, qg, kg, vtg);
  k_attn2<<<dim3(2048), dim3(256), 0, stream>>>(qg, kg, vtg, biasf, attnout);
  k_proj<<<dim3(2048), dim3(256), 0, stream>>>(attnout, wpf, proj_b, z0, zt);
  k_mlp<<<dim3(2048), dim3(256), 0, stream>>>(zt, ln2_g, ln2_b,
      w1f, fc1_b, w2f, fc2_b, out);
}